// Round 5
// baseline (284.324 us; speedup 1.0000x reference)
//
#include <hip/hip_runtime.h>
#include <math.h>

// Legendre-KAN: y[n,o] = sum_{i,d} P_d(xn[n,i]) * coeffs[o,i,d] + bias[o]
// GEMM: A[65536 x 4096] (on-the-fly scaled-Legendre basis, bf16) * B[4096 x 64] (bf16).
// R5: B pinned in LDS (8-kt windows, shared by all 4 waves of a block) -> no L3-latency
// B loads in the K-loop (R4's stall). 32-row waves, K-split 4 ACROSS blocks, y reduced
// via atomicAdd into bias-initialized output. 8192 waves -> ~4 waves/SIMD resident.

typedef __bf16 bf16x8 __attribute__((ext_vector_type(8)));
typedef float f32x4 __attribute__((ext_vector_type(4)));

// ---------------- pass 1a: per-block min/max ----------------
__global__ __launch_bounds__(256) void k_minmax_partial(
    const float4* __restrict__ x4, int n4, float* __restrict__ pmn, float* __restrict__ pmx)
{
  float mn = 3.4e38f, mx = -3.4e38f;
  int stride = gridDim.x * 256;
  for (int i = blockIdx.x * 256 + threadIdx.x; i < n4; i += stride) {
    float4 v = x4[i];
    mn = fminf(mn, fminf(fminf(v.x, v.y), fminf(v.z, v.w)));
    mx = fmaxf(mx, fmaxf(fmaxf(v.x, v.y), fmaxf(v.z, v.w)));
  }
  #pragma unroll
  for (int off = 32; off > 0; off >>= 1) {
    mn = fminf(mn, __shfl_down(mn, off));
    mx = fmaxf(mx, __shfl_down(mx, off));
  }
  __shared__ float smn[4], smx[4];
  int w = threadIdx.x >> 6;
  if ((threadIdx.x & 63) == 0) { smn[w] = mn; smx[w] = mx; }
  __syncthreads();
  if (threadIdx.x == 0) {
    pmn[blockIdx.x] = fminf(fminf(smn[0], smn[1]), fminf(smn[2], smn[3]));
    pmx[blockIdx.x] = fmaxf(fmaxf(smx[0], smx[1]), fmaxf(smx[2], smx[3]));
  }
}

// ---------------- fused: prepB (0..127) + minmax final (128) + y=bias init (129..1152) ----
// Bws[(kt*4+ct)*64 + lane][j] = coeffs[o=ct*16+(lane&15)][i=kt*4+(lane>>4)][d=j] * g[j]
__global__ __launch_bounds__(256) void k_prep_final(
    const float* __restrict__ coeffs, bf16x8* __restrict__ Bws,
    const float* __restrict__ pmn, const float* __restrict__ pmx, int nb,
    float* __restrict__ so, float* __restrict__ y, const float* __restrict__ bias,
    int doB)
{
  int b = blockIdx.x;
  if (b < 128) {
    if (!doB) return;
    int t = b * 256 + threadIdx.x;            // [0, 32768)
    int lane = t & 63;
    int tile = t >> 6;                        // kt*4 + ct
    int ct = tile & 3;
    int kt = tile >> 2;
    int i = kt * 4 + (lane >> 4);
    int o = ct * 16 + (lane & 15);
    const float4* cp = (const float4*)(coeffs + ((size_t)o * 512 + i) * 8);
    float4 c0 = cp[0], c1 = cp[1];
    // g_n: P_n = g_n * S_n;  g = {1,1,1.5,2.5,4.375,7.875,14.4375,26.8125}
    bf16x8 v;
    v[0] = (__bf16)(c0.x);
    v[1] = (__bf16)(c0.y);
    v[2] = (__bf16)(c0.z * 1.5f);
    v[3] = (__bf16)(c0.w * 2.5f);
    v[4] = (__bf16)(c1.x * 4.375f);
    v[5] = (__bf16)(c1.y * 7.875f);
    v[6] = (__bf16)(c1.z * 14.4375f);
    v[7] = (__bf16)(c1.w * 26.8125f);
    Bws[(size_t)(kt * 4 + ct) * 64 + lane] = v;
  } else if (b == 128) {
    float mn = 3.4e38f, mx = -3.4e38f;
    for (int i = threadIdx.x; i < nb; i += 256) {
      mn = fminf(mn, pmn[i]);
      mx = fmaxf(mx, pmx[i]);
    }
    #pragma unroll
    for (int off = 32; off > 0; off >>= 1) {
      mn = fminf(mn, __shfl_down(mn, off));
      mx = fmaxf(mx, __shfl_down(mx, off));
    }
    __shared__ float smn[4], smx[4];
    int w = threadIdx.x >> 6;
    if ((threadIdx.x & 63) == 0) { smn[w] = mn; smx[w] = mx; }
    __syncthreads();
    if (threadIdx.x == 0) {
      mn = fminf(fminf(smn[0], smn[1]), fminf(smn[2], smn[3]));
      mx = fmaxf(fmaxf(smx[0], smx[1]), fmaxf(smx[2], smx[3]));
      float r = mx - mn;
      so[0] = 2.0f / r;               // scale
      so[1] = -2.0f * mn / r - 1.0f;  // offset:  xn = x*s + o
    }
  } else {
    // y[n][o] = bias[o]; 1024 blocks x 1024 float4 each (y = 1,048,576 float4)
    int base = (b - 129) * 1024;
    const float4* b4 = (const float4*)bias;   // 16 float4 covering o=0..63
    float4* y4 = (float4*)y;
    #pragma unroll
    for (int r = 0; r < 4; ++r) {
      int j = base + r * 256 + threadIdx.x;
      y4[j] = b4[j & 15];
    }
  }
}

// ---------------- pass 2: fused basis + MFMA GEMM ----------------
// Block = 256 thr (4 waves). rowgroup = bx>>2 (128 rows, wave w -> 32 rows),
// K-quarter qK = bx&3 (kt in [qK*32, qK*32+32)). B window = 8 kt = 32 KiB LDS,
// staged by all threads, refreshed 4x. In-loop: B via ds_read_b128 (dist-1 ring),
// x via direct global gather (64B-line reuse across 4 kt, dist-2 ring).
// Output: atomicAdd into bias-initialized y.
__global__ __launch_bounds__(256, 4) void k_main(
    const float* __restrict__ x, const bf16x8* __restrict__ Bws,
    const float* __restrict__ so, float* __restrict__ y)
{
  __shared__ __align__(16) float4 smem[2048];   // 32 KiB: 8 kt x 4 ct x 64 lanes x 16 B

  const float s = so[0], off = so[1];
  const int t    = threadIdx.x;
  const int lane = t & 63;
  const int w    = t >> 6;
  const int m    = lane & 15;
  const int quad = lane >> 4;
  const int bx   = blockIdx.x;
  const int qK   = bx & 3;
  const size_t rowbase = ((size_t)(bx >> 2)) * 128 + (size_t)w * 32;
  const int kb0 = qK * 32;

  // x gather bases (already offset by kb0 and quad); element offset = l*4, l in [0,32)
  const float* xq0 = x + (rowbase +      m) * 512 + (size_t)kb0 * 4 + quad;
  const float* xq1 = x + (rowbase + 16 + m) * 512 + (size_t)kb0 * 4 + quad;

  // B window source: kt stride = 4 frags * 64 lanes * 16 B = 4096 B
  const float4* bsrc = (const float4*)((const char*)Bws + (size_t)kb0 * 4096);

  f32x4 acc[2][4];
  #pragma unroll
  for (int f = 0; f < 2; ++f)
    #pragma unroll
    for (int ct = 0; ct < 4; ++ct) acc[f][ct] = (f32x4){0.f, 0.f, 0.f, 0.f};

  // scaled-recurrence constants c_n = (n-1)^2 / ((2n-1)(2n-3))
  const float C2 = 0.33333334f, C3 = 0.26666668f, C4 = 0.25714287f;
  const float C5 = 0.25396827f, C6 = 0.25252524f, C7 = 0.25174826f;

  // x prefetch ring, distance 2, slots (l & 3)
  float xr[4][2];
  xr[0][0] = xq0[0];  xr[0][1] = xq1[0];
  xr[1][0] = xq0[4];  xr[1][1] = xq1[4];

  const bf16x8* bw = (const bf16x8*)smem;

  for (int wi = 0; wi < 4; ++wi) {
    // ---- stage B window wi (32 KiB) ----
    __syncthreads();                       // previous window fully consumed
    {
      const float4* g = bsrc + (size_t)wi * 2048;
      float4 a0 = g[t], a1 = g[t + 256], a2 = g[t + 512], a3 = g[t + 768];
      smem[t] = a0; smem[t + 256] = a1; smem[t + 512] = a2; smem[t + 768] = a3;
      float4 b0 = g[t + 1024], b1 = g[t + 1280], b2 = g[t + 1536], b3 = g[t + 1792];
      smem[t + 1024] = b0; smem[t + 1280] = b1; smem[t + 1536] = b2; smem[t + 1792] = b3;
    }
    __syncthreads();

    // B frag ring, distance 1, slots (kl & 1)
    bf16x8 Bq[2][4];
    #pragma unroll
    for (int ct = 0; ct < 4; ++ct) Bq[0][ct] = bw[ct * 64 + lane];

    #pragma unroll
    for (int kl = 0; kl < 8; ++kl) {
      const int l = wi * 8 + kl;           // [0,32)

      // prefetch next B frags from LDS
      if (kl < 7) {
        #pragma unroll
        for (int ct = 0; ct < 4; ++ct)
          Bq[(kl + 1) & 1][ct] = bw[((kl + 1) * 4 + ct) * 64 + lane];
      }
      // prefetch x for l+2 (clamped; slots (kl+2)&3 since 8 % 4 == 0)
      {
        const int lp = (l + 2 < 32) ? (l + 2) : 31;
        xr[(kl + 2) & 3][0] = xq0[lp * 4];
        xr[(kl + 2) & 3][1] = xq1[lp * 4];
      }

      // scaled Legendre basis: S0=1, S1=xn, S_n = xn*S_{n-1} - c_n*S_{n-2}
      bf16x8 a[2];
      #pragma unroll
      for (int f = 0; f < 2; ++f) {
        float xn = fmaf(xr[kl & 3][f], s, off);
        float s2 = fmaf(xn, xn, -C2);
        float s3 = (s2 - C3) * xn;
        float s4 = fmaf(xn, s3, -(C4 * s2));
        float s5 = fmaf(xn, s4, -(C5 * s3));
        float s6 = fmaf(xn, s5, -(C6 * s4));
        float s7 = fmaf(xn, s6, -(C7 * s5));
        bf16x8 av;
        av[0] = (__bf16)1.0f; av[1] = (__bf16)xn; av[2] = (__bf16)s2; av[3] = (__bf16)s3;
        av[4] = (__bf16)s4;   av[5] = (__bf16)s5; av[6] = (__bf16)s6; av[7] = (__bf16)s7;
        a[f] = av;
      }

      #pragma unroll
      for (int f = 0; f < 2; ++f)
        #pragma unroll
        for (int ct = 0; ct < 4; ++ct)
          acc[f][ct] = __builtin_amdgcn_mfma_f32_16x16x32_bf16(a[f], Bq[kl & 1][ct], acc[f][ct], 0, 0, 0);
    }
  }

  // ---- epilogue: atomic reduce into y (C/D layout: col = m, row = quad*4 + r) ----
  #pragma unroll
  for (int f = 0; f < 2; ++f) {
    float* yp = y + (rowbase + f * 16 + quad * 4) * 64 + m;
    #pragma unroll
    for (int ct = 0; ct < 4; ++ct)
      #pragma unroll
      for (int r = 0; r < 4; ++r)
        atomicAdd(yp + r * 64 + ct * 16, acc[f][ct][r]);
  }
}

// ---------------- fallback (no workspace): 16 rows/wave, direct coeff loads ----
__global__ __launch_bounds__(256) void k_main_simple(
    const float* __restrict__ x, const float* __restrict__ coeffs,
    const float* __restrict__ bias, const float* __restrict__ so, float* __restrict__ y)
{
  const float s = so[0], off = so[1];
  const int lane = threadIdx.x & 63;
  const int w    = threadIdx.x >> 6;
  const int m    = lane & 15;
  const int quad = lane >> 4;
  const int rowA = blockIdx.x * 64 + w * 16 + m;
  const float* xp = x + (size_t)rowA * 512 + quad;

  f32x4 acc0 = {0.f,0.f,0.f,0.f}, acc1 = acc0, acc2 = acc0, acc3 = acc0;
  const float c3a = 5.f/3.f, c3b = 2.f/3.f, c6a = 11.f/6.f, c6b = 5.f/6.f, c7a = 13.f/7.f, c7b = 6.f/7.f;

  for (int kt = 0; kt < 128; ++kt) {
    float xv = xp[kt * 4];
    int i = kt * 4 + quad;
    bf16x8 b[4];
    #pragma unroll
    for (int ct = 0; ct < 4; ++ct) {
      const float* cp = coeffs + ((size_t)(ct * 16 + m) * 512 + i) * 8;
      #pragma unroll
      for (int j = 0; j < 8; ++j) b[ct][j] = (__bf16)cp[j];
    }
    float xn = fmaf(xv, s, off);
    float p2 = fmaf(1.5f * xn, xn, -0.5f);
    float p3 = fmaf(c3a * xn, p2, -(c3b * xn));
    float p4 = fmaf(1.75f * xn, p3, -(0.75f * p2));
    float p5 = fmaf(1.8f * xn, p4, -(0.8f * p3));
    float p6 = fmaf(c6a * xn, p5, -(c6b * p4));
    float p7 = fmaf(c7a * xn, p6, -(c7b * p5));
    bf16x8 a;
    a[0] = (__bf16)1.0f; a[1] = (__bf16)xn; a[2] = (__bf16)p2; a[3] = (__bf16)p3;
    a[4] = (__bf16)p4;   a[5] = (__bf16)p5; a[6] = (__bf16)p6; a[7] = (__bf16)p7;
    acc0 = __builtin_amdgcn_mfma_f32_16x16x32_bf16(a, b[0], acc0, 0, 0, 0);
    acc1 = __builtin_amdgcn_mfma_f32_16x16x32_bf16(a, b[1], acc1, 0, 0, 0);
    acc2 = __builtin_amdgcn_mfma_f32_16x16x32_bf16(a, b[2], acc2, 0, 0, 0);
    acc3 = __builtin_amdgcn_mfma_f32_16x16x32_bf16(a, b[3], acc3, 0, 0, 0);
  }
  float b0v = bias[m], b1v = bias[16+m], b2v = bias[32+m], b3v = bias[48+m];
  float* yp = y + ((size_t)(blockIdx.x * 64 + w * 16 + quad * 4)) * 64 + m;
  #pragma unroll
  for (int r = 0; r < 4; ++r) {
    yp[r*64+ 0] = acc0[r] + b0v;
    yp[r*64+16] = acc1[r] + b1v;
    yp[r*64+32] = acc2[r] + b2v;
    yp[r*64+48] = acc3[r] + b3v;
  }
}

extern "C" void kernel_launch(void* const* d_in, const int* in_sizes, int n_in,
                              void* d_out, int out_size, void* d_ws, size_t ws_size,
                              hipStream_t stream)
{
  const float* x      = (const float*)d_in[0];
  const float* coeffs = (const float*)d_in[1];
  const float* bias   = (const float*)d_in[2];
  float* y = (float*)d_out;

  long nx = (long)in_sizes[0];        // 33,554,432
  int  N  = (int)(nx / 512);          // 65536 rows
  int  n4 = (int)(nx / 4);

  float*  so  = (float*)d_ws;
  float*  pmn = (float*)d_ws + 16;
  float*  pmx = pmn + 4096;
  bf16x8* Bws = (bf16x8*)((char*)d_ws + 65536);

  bool pre = ws_size >= (size_t)(65536 + 4096 * 64 * 2 + 4096);

  const int MMB = 4096;
  k_minmax_partial<<<MMB, 256, 0, stream>>>((const float4*)x, n4, pmn, pmx);
  k_prep_final<<<1153, 256, 0, stream>>>(coeffs, Bws, pmn, pmx, MMB, so, y, bias, pre ? 1 : 0);

  if (pre) {
    k_main<<<(N / 128) * 4, 256, 0, stream>>>(x, Bws, so, y);
  } else {
    k_main_simple<<<N / 64, 256, 0, stream>>>(x, coeffs, bias, so, y);
  }
}

// Round 6
// 266.652 us; speedup vs baseline: 1.0663x; 1.0663x over previous
//
#include <hip/hip_runtime.h>
#include <math.h>

// Legendre-KAN: y[n,o] = sum_{i,d} P_d(xn[n,i]) * coeffs[o,i,d] + bias[o]
// GEMM: A[65536 x 4096] (on-the-fly scaled-Legendre basis, bf16) * B[4096 x 64] (bf16).
// R6: kill the transposed x gather (R2-R5's shared TA bottleneck). x loaded COALESCED,
// basis computed at staging time, A-fragments written to LDS (stride-17 -> 2-way only).
// K-loop = pure ds_read_b128 + MFMA (no VALU, no global). B window co-staged in LDS.
// K-split 4 across blocks, atomicAdd into bias-initialized y.

typedef __bf16 bf16x8 __attribute__((ext_vector_type(8)));
typedef float f32x4 __attribute__((ext_vector_type(4)));

#define ASTRIDE 17   // A entry stride per row (16 i + 1 pad) in 16-B units

// ---------------- pass 1a: per-block min/max ----------------
__global__ __launch_bounds__(256) void k_minmax_partial(
    const float4* __restrict__ x4, int n4, float* __restrict__ pmn, float* __restrict__ pmx)
{
  float mn = 3.4e38f, mx = -3.4e38f;
  int stride = gridDim.x * 256;
  for (int i = blockIdx.x * 256 + threadIdx.x; i < n4; i += stride) {
    float4 v = x4[i];
    mn = fminf(mn, fminf(fminf(v.x, v.y), fminf(v.z, v.w)));
    mx = fmaxf(mx, fmaxf(fmaxf(v.x, v.y), fmaxf(v.z, v.w)));
  }
  #pragma unroll
  for (int off = 32; off > 0; off >>= 1) {
    mn = fminf(mn, __shfl_down(mn, off));
    mx = fmaxf(mx, __shfl_down(mx, off));
  }
  __shared__ float smn[4], smx[4];
  int w = threadIdx.x >> 6;
  if ((threadIdx.x & 63) == 0) { smn[w] = mn; smx[w] = mx; }
  __syncthreads();
  if (threadIdx.x == 0) {
    pmn[blockIdx.x] = fminf(fminf(smn[0], smn[1]), fminf(smn[2], smn[3]));
    pmx[blockIdx.x] = fmaxf(fmaxf(smx[0], smx[1]), fmaxf(smx[2], smx[3]));
  }
}

// ---------------- fused: prepB (0..127) + minmax final (128) + y=bias init (129..1152) ----
// Bws[(kt*4+ct)*64 + lane][j] = coeffs[o=ct*16+(lane&15)][i=kt*4+(lane>>4)][d=j] * g[j]
__global__ __launch_bounds__(256) void k_prep_final(
    const float* __restrict__ coeffs, bf16x8* __restrict__ Bws,
    const float* __restrict__ pmn, const float* __restrict__ pmx, int nb,
    float* __restrict__ so, float* __restrict__ y, const float* __restrict__ bias,
    int doB)
{
  int b = blockIdx.x;
  if (b < 128) {
    if (!doB) return;
    int t = b * 256 + threadIdx.x;            // [0, 32768)
    int lane = t & 63;
    int tile = t >> 6;                        // kt*4 + ct
    int ct = tile & 3;
    int kt = tile >> 2;
    int i = kt * 4 + (lane >> 4);
    int o = ct * 16 + (lane & 15);
    const float4* cp = (const float4*)(coeffs + ((size_t)o * 512 + i) * 8);
    float4 c0 = cp[0], c1 = cp[1];
    // g_n: P_n = g_n * S_n;  g = {1,1,1.5,2.5,4.375,7.875,14.4375,26.8125}
    bf16x8 v;
    v[0] = (__bf16)(c0.x);
    v[1] = (__bf16)(c0.y);
    v[2] = (__bf16)(c0.z * 1.5f);
    v[3] = (__bf16)(c0.w * 2.5f);
    v[4] = (__bf16)(c1.x * 4.375f);
    v[5] = (__bf16)(c1.y * 7.875f);
    v[6] = (__bf16)(c1.z * 14.4375f);
    v[7] = (__bf16)(c1.w * 26.8125f);
    Bws[(size_t)(kt * 4 + ct) * 64 + lane] = v;
  } else if (b == 128) {
    float mn = 3.4e38f, mx = -3.4e38f;
    for (int i = threadIdx.x; i < nb; i += 256) {
      mn = fminf(mn, pmn[i]);
      mx = fmaxf(mx, pmx[i]);
    }
    #pragma unroll
    for (int off = 32; off > 0; off >>= 1) {
      mn = fminf(mn, __shfl_down(mn, off));
      mx = fmaxf(mx, __shfl_down(mx, off));
    }
    __shared__ float smn[4], smx[4];
    int w = threadIdx.x >> 6;
    if ((threadIdx.x & 63) == 0) { smn[w] = mn; smx[w] = mx; }
    __syncthreads();
    if (threadIdx.x == 0) {
      mn = fminf(fminf(smn[0], smn[1]), fminf(smn[2], smn[3]));
      mx = fmaxf(fmaxf(smx[0], smx[1]), fmaxf(smx[2], smx[3]));
      float r = mx - mn;
      so[0] = 2.0f / r;               // scale
      so[1] = -2.0f * mn / r - 1.0f;  // offset:  xn = x*s + o
    }
  } else {
    // y[n][o] = bias[o]; 1024 blocks x 1024 float4 each (y = 1,048,576 float4)
    int base = (b - 129) * 1024;
    const float4* b4 = (const float4*)bias;   // 16 float4 covering o=0..63
    float4* y4 = (float4*)y;
    #pragma unroll
    for (int r = 0; r < 4; ++r) {
      int j = base + r * 256 + threadIdx.x;
      y4[j] = b4[j & 15];
    }
  }
}

// ---------------- pass 2: staged-basis MFMA GEMM ----------------
// Block = 256 thr (4 waves), 128 rows, K-quarter qK = bx&3 (32 kt). Window = 4 kt (16 i):
//   stage: thread t loads x[row=t>>1][8 i's] coalesced (2 float4), computes 8 basis
//   fragments (bf16x8), ds_write_b128 into As[row*17 + i]; B window (16 KiB) co-staged.
//   K-loop: per kt, 2 A-frag + 4 B-frag ds_read_b128 + 8 MFMA. No VALU, no global.
// Epilogue: atomicAdd into bias-initialized y.
__global__ __launch_bounds__(256, 3) void k_main(
    const float* __restrict__ x, const bf16x8* __restrict__ Bws,
    const float* __restrict__ so, float* __restrict__ y)
{
  __shared__ __align__(16) char smem[51200];   // A: 128*17*16=34816, B: 16384
  bf16x8* As = (bf16x8*)smem;
  bf16x8* Bs = (bf16x8*)(smem + 34816);
  float4* Bs4 = (float4*)Bs;

  const float s = so[0], off = so[1];
  const int t    = threadIdx.x;
  const int lane = t & 63;
  const int w    = t >> 6;
  const int m    = lane & 15;
  const int quad = lane >> 4;
  const int bx   = blockIdx.x;
  const int qK   = bx & 3;
  const size_t rowbase = ((size_t)(bx >> 2)) * 128;

  // staging: thread t -> row t>>1, i-half t&1 (8 i's per window)
  const int srow  = t >> 1;
  const int shalf = t & 1;
  const float* xg = x + (rowbase + srow) * 512 + qK * 128 + shalf * 8;
  const int awbase = srow * ASTRIDE + shalf * 8;

  // B window source: this K-quarter's 32 kt start; window = 1024 float4
  const float4* bsrc = (const float4*)(Bws + (size_t)qK * 32 * 256);

  // A read bases: row = w*32 + f*16 + m, i = ktl*4 + quad
  int arb[2];
  #pragma unroll
  for (int f = 0; f < 2; ++f) arb[f] = (w * 32 + f * 16 + m) * ASTRIDE + quad;

  f32x4 acc[2][4];
  #pragma unroll
  for (int f = 0; f < 2; ++f)
    #pragma unroll
    for (int ct = 0; ct < 4; ++ct) acc[f][ct] = (f32x4){0.f, 0.f, 0.f, 0.f};

  // scaled-recurrence constants c_n = (n-1)^2 / ((2n-1)(2n-3))
  const float C2 = 0.33333334f, C3 = 0.26666668f, C4 = 0.25714287f;
  const float C5 = 0.25396827f, C6 = 0.25252524f, C7 = 0.25174826f;

  // prologue: window-0 globals into regs
  float4 xv0 = *(const float4*)(xg);
  float4 xv1 = *(const float4*)(xg + 4);
  float4 bv0 = bsrc[t], bv1 = bsrc[t + 256], bv2 = bsrc[t + 512], bv3 = bsrc[t + 768];

  for (int wi = 0; wi < 8; ++wi) {
    // ---- stage: basis for 8 x-elements -> A frags in LDS; B window copy ----
    float xe[8] = {xv0.x, xv0.y, xv0.z, xv0.w, xv1.x, xv1.y, xv1.z, xv1.w};
    #pragma unroll
    for (int e = 0; e < 8; ++e) {
      float xn = fmaf(xe[e], s, off);
      float s2 = fmaf(xn, xn, -C2);
      float s3 = (s2 - C3) * xn;
      float s4 = fmaf(xn, s3, -(C4 * s2));
      float s5 = fmaf(xn, s4, -(C5 * s3));
      float s6 = fmaf(xn, s5, -(C6 * s4));
      float s7 = fmaf(xn, s6, -(C7 * s5));
      bf16x8 av;
      av[0] = (__bf16)1.0f; av[1] = (__bf16)xn; av[2] = (__bf16)s2; av[3] = (__bf16)s3;
      av[4] = (__bf16)s4;   av[5] = (__bf16)s5; av[6] = (__bf16)s6; av[7] = (__bf16)s7;
      As[awbase + e] = av;
    }
    Bs4[t] = bv0; Bs4[t + 256] = bv1; Bs4[t + 512] = bv2; Bs4[t + 768] = bv3;
    __syncthreads();

    // ---- prefetch next window's globals (overlaps with MFMA below) ----
    if (wi < 7) {
      const float* xgn = xg + (wi + 1) * 16;
      xv0 = *(const float4*)(xgn);
      xv1 = *(const float4*)(xgn + 4);
      const float4* bn = bsrc + (size_t)(wi + 1) * 1024;
      bv0 = bn[t]; bv1 = bn[t + 256]; bv2 = bn[t + 512]; bv3 = bn[t + 768];
    }

    // ---- K-loop: 4 kt, software-pipelined LDS reads (dist 1) ----
    bf16x8 Aq[2][2], Bq[2][4];
    #pragma unroll
    for (int f = 0; f < 2; ++f) Aq[0][f] = As[arb[f]];
    #pragma unroll
    for (int ct = 0; ct < 4; ++ct) Bq[0][ct] = Bs[ct * 64 + lane];

    #pragma unroll
    for (int ktl = 0; ktl < 4; ++ktl) {
      if (ktl < 3) {
        #pragma unroll
        for (int f = 0; f < 2; ++f) Aq[(ktl + 1) & 1][f] = As[arb[f] + (ktl + 1) * 4];
        #pragma unroll
        for (int ct = 0; ct < 4; ++ct) Bq[(ktl + 1) & 1][ct] = Bs[((ktl + 1) * 4 + ct) * 64 + lane];
      }
      #pragma unroll
      for (int f = 0; f < 2; ++f)
        #pragma unroll
        for (int ct = 0; ct < 4; ++ct)
          acc[f][ct] = __builtin_amdgcn_mfma_f32_16x16x32_bf16(Aq[ktl & 1][f], Bq[ktl & 1][ct], acc[f][ct], 0, 0, 0);
    }
    __syncthreads();
  }

  // ---- epilogue: atomic reduce into y (C/D layout: col = m, row = quad*4 + r) ----
  #pragma unroll
  for (int f = 0; f < 2; ++f) {
    float* yp = y + (rowbase + w * 32 + f * 16 + quad * 4) * 64 + m;
    #pragma unroll
    for (int ct = 0; ct < 4; ++ct)
      #pragma unroll
      for (int r = 0; r < 4; ++r)
        atomicAdd(yp + r * 64 + ct * 16, acc[f][ct][r]);
  }
}

// ---------------- fallback (no workspace): 16 rows/wave, direct coeff loads ----
__global__ __launch_bounds__(256) void k_main_simple(
    const float* __restrict__ x, const float* __restrict__ coeffs,
    const float* __restrict__ bias, const float* __restrict__ so, float* __restrict__ y)
{
  const float s = so[0], off = so[1];
  const int lane = threadIdx.x & 63;
  const int w    = threadIdx.x >> 6;
  const int m    = lane & 15;
  const int quad = lane >> 4;
  const int rowA = blockIdx.x * 64 + w * 16 + m;
  const float* xp = x + (size_t)rowA * 512 + quad;

  f32x4 acc0 = {0.f,0.f,0.f,0.f}, acc1 = acc0, acc2 = acc0, acc3 = acc0;
  const float c3a = 5.f/3.f, c3b = 2.f/3.f, c6a = 11.f/6.f, c6b = 5.f/6.f, c7a = 13.f/7.f, c7b = 6.f/7.f;

  for (int kt = 0; kt < 128; ++kt) {
    float xv = xp[kt * 4];
    int i = kt * 4 + quad;
    bf16x8 b[4];
    #pragma unroll
    for (int ct = 0; ct < 4; ++ct) {
      const float* cp = coeffs + ((size_t)(ct * 16 + m) * 512 + i) * 8;
      #pragma unroll
      for (int j = 0; j < 8; ++j) b[ct][j] = (__bf16)cp[j];
    }
    float xn = fmaf(xv, s, off);
    float p2 = fmaf(1.5f * xn, xn, -0.5f);
    float p3 = fmaf(c3a * xn, p2, -(c3b * xn));
    float p4 = fmaf(1.75f * xn, p3, -(0.75f * p2));
    float p5 = fmaf(1.8f * xn, p4, -(0.8f * p3));
    float p6 = fmaf(c6a * xn, p5, -(c6b * p4));
    float p7 = fmaf(c7a * xn, p6, -(c7b * p5));
    bf16x8 a;
    a[0] = (__bf16)1.0f; a[1] = (__bf16)xn; a[2] = (__bf16)p2; a[3] = (__bf16)p3;
    a[4] = (__bf16)p4;   a[5] = (__bf16)p5; a[6] = (__bf16)p6; a[7] = (__bf16)p7;
    acc0 = __builtin_amdgcn_mfma_f32_16x16x32_bf16(a, b[0], acc0, 0, 0, 0);
    acc1 = __builtin_amdgcn_mfma_f32_16x16x32_bf16(a, b[1], acc1, 0, 0, 0);
    acc2 = __builtin_amdgcn_mfma_f32_16x16x32_bf16(a, b[2], acc2, 0, 0, 0);
    acc3 = __builtin_amdgcn_mfma_f32_16x16x32_bf16(a, b[3], acc3, 0, 0, 0);
  }
  float b0v = bias[m], b1v = bias[16+m], b2v = bias[32+m], b3v = bias[48+m];
  float* yp = y + ((size_t)(blockIdx.x * 64 + w * 16 + quad * 4)) * 64 + m;
  #pragma unroll
  for (int r = 0; r < 4; ++r) {
    yp[r*64+ 0] = acc0[r] + b0v;
    yp[r*64+16] = acc1[r] + b1v;
    yp[r*64+32] = acc2[r] + b2v;
    yp[r*64+48] = acc3[r] + b3v;
  }
}

extern "C" void kernel_launch(void* const* d_in, const int* in_sizes, int n_in,
                              void* d_out, int out_size, void* d_ws, size_t ws_size,
                              hipStream_t stream)
{
  const float* x      = (const float*)d_in[0];
  const float* coeffs = (const float*)d_in[1];
  const float* bias   = (const float*)d_in[2];
  float* y = (float*)d_out;

  long nx = (long)in_sizes[0];        // 33,554,432
  int  N  = (int)(nx / 512);          // 65536 rows
  int  n4 = (int)(nx / 4);

  float*  so  = (float*)d_ws;
  float*  pmn = (float*)d_ws + 16;
  float*  pmx = pmn + 4096;
  bf16x8* Bws = (bf16x8*)((char*)d_ws + 65536);

  bool pre = ws_size >= (size_t)(65536 + 4096 * 64 * 2 + 4096);

  const int MMB = 4096;
  k_minmax_partial<<<MMB, 256, 0, stream>>>((const float4*)x, n4, pmn, pmx);
  k_prep_final<<<1153, 256, 0, stream>>>(coeffs, Bws, pmn, pmx, MMB, so, y, bias, pre ? 1 : 0);

  if (pre) {
    k_main<<<(N / 128) * 4, 256, 0, stream>>>(x, Bws, so, y);
  } else {
    k_main_simple<<<N / 64, 256, 0, stream>>>(x, coeffs, bias, so, y);
  }
}